// Round 19
// baseline (97.135 us; speedup 1.0000x reference)
//
#include <hip/hip_runtime.h>

typedef float f32x4 __attribute__((ext_vector_type(4)));

#define D_IN 1024

// tanh(x) = 1 - 2/(exp(2x)+1): v_exp + v_rcp, robust for all x
__device__ __forceinline__ float fast_tanh(float x) {
  float e = __expf(2.0f * x);
  return 1.0f - 2.0f * __builtin_amdgcn_rcpf(e + 1.0f);
}

// ---------------------------------------------------------------------------
// DIAGNOSTIC v2: round-15 k1 (16 rows/wave, 4 lanes/row, 512 blocks) with
// REP=4 and the x pointer LAUNDERED through asm each rep so LICM cannot hoist
// the loads/FMAs (round-18 lesson: un-laundered REP was fully hoisted).
// Stores are idempotent rewrites; k2 unchanged -> output correct.
// ---------------------------------------------------------------------------
__global__ __launch_bounds__(256) void dots_kernel(
    const float* __restrict__ x, const float* __restrict__ W1,
    float* __restrict__ dots, int B) {
  __shared__ f32x4 W1L[1024];  // W1L[j*256 + i] = W1[j][4i..4i+3]

  const int tid = threadIdx.x;
  {
    const f32x4* wp = reinterpret_cast<const f32x4*>(W1);
#pragma unroll
    for (int k = 0; k < 4; ++k) W1L[k * 256 + tid] = wp[k * 256 + tid];
  }
  __syncthreads();

  const int lane = tid & 63;
  const int p = lane & 3;        // d-phase: owns [g*64 + p*16, +16) for g=0..15
  const int wave = blockIdx.x * 4 + (tid >> 6);
  const int row = wave * 16 + (lane >> 2);
  if (row >= B) return;

  const float* xr = x + (size_t)row * D_IN;

  for (int rep = 0; rep < 4; ++rep) {
    // launder the pointer: compiler must assume it changed -> loads and the
    // dependent FMA chain re-execute every rep (defeats LICM/DCE)
    const float* xrl = xr;
    asm volatile("" : "+v"(xrl));

    float acc[4] = {0.f, 0.f, 0.f, 0.f};

#pragma unroll
    for (int g = 0; g < 16; ++g) {
      const int db = g * 64 + p * 16;  // float index of this lane's 16-float slice
      f32x4 xv[4];
#pragma unroll
      for (int k = 0; k < 4; ++k)
        xv[k] = *reinterpret_cast<const f32x4*>(xrl + db + 4 * k);
#pragma unroll
      for (int k = 0; k < 4; ++k) {
        const int wi = (db >> 2) + k;
        f32x4 xk = xv[k];
#pragma unroll
        for (int j = 0; j < 4; ++j) {
          f32x4 w = W1L[j * 256 + wi];
          acc[j] = fmaf(xk.x, w.x, acc[j]);
          acc[j] = fmaf(xk.y, w.y, acc[j]);
          acc[j] = fmaf(xk.z, w.z, acc[j]);
          acc[j] = fmaf(xk.w, w.w, acc[j]);
        }
      }
    }

    // reduce each dot over the 4 phase-lanes (2 butterfly levels)
#pragma unroll
    for (int j = 0; j < 4; ++j) {
      acc[j] += __shfl_xor(acc[j], 1);
      acc[j] += __shfl_xor(acc[j], 2);
    }
    // lane p stores feature p -> dots[row][p]; idempotent across reps
    float outv = (p == 0) ? acc[0] : (p == 1) ? acc[1] : (p == 2) ? acc[2] : acc[3];
    dots[(size_t)row * 4 + p] = outv;
  }
}

// ---------------------------------------------------------------------------
// k2: tail (unchanged, validated). Per row: uniform 16B load of dots[r] ->
// tanh/sincos -> rank-1 product state -> qf_i = s^T M_i s -> mu/logvar.
// ---------------------------------------------------------------------------
__global__ __launch_bounds__(256) void tail_kernel(
    const float* __restrict__ dots, const float* __restrict__ b1,
    const float* __restrict__ theta,
    const float* __restrict__ Wmu, const float* __restrict__ bmu,
    const float* __restrict__ Wlv, const float* __restrict__ blv,
    float* __restrict__ out, int B) {
  __shared__ float Vre[16][17];
  __shared__ float Vim[16][17];
  __shared__ float Mlds[4][16][16];

  const int tid = threadIdx.x;

  // ---- prologue: evolve V on threads 0..15 ----
  if (tid < 16) {
    float re[16], im[16];
#pragma unroll
    for (int z = 0; z < 16; ++z) { re[z] = 0.f; im[z] = 0.f; }
    re[tid] = 1.f;
    for (int layer = 0; layer < 2; ++layer) {
#pragma unroll
      for (int q = 0; q < 4; ++q) {
        float th = theta[layer * 4 + q];
        float s, c;
        __sincosf(0.5f * th, &s, &c);
        // Rx
#pragma unroll
        for (int z = 0; z < 16; ++z) {
          if (!((z >> q) & 1)) {
            int z1 = z | (1 << q);
            float ar = re[z], ai = im[z], br = re[z1], bi = im[z1];
            re[z]  = c * ar + s * bi;  im[z]  = c * ai - s * br;
            re[z1] = c * br + s * ai;  im[z1] = c * bi - s * ar;
          }
        }
        // Ry
#pragma unroll
        for (int z = 0; z < 16; ++z) {
          if (!((z >> q) & 1)) {
            int z1 = z | (1 << q);
            float ar = re[z], ai = im[z], br = re[z1], bi = im[z1];
            re[z]  = c * ar - s * br;  im[z]  = c * ai - s * bi;
            re[z1] = s * ar + c * br;  im[z1] = s * ai + c * bi;
          }
        }
        // Rz
#pragma unroll
        for (int z = 0; z < 16; ++z) {
          if (!((z >> q) & 1)) {
            int z1 = z | (1 << q);
            float ar = re[z], ai = im[z], br = re[z1], bi = im[z1];
            re[z]  = c * ar + s * ai;  im[z]  = c * ai - s * ar;
            re[z1] = c * br - s * bi;  im[z1] = c * bi + s * br;
          }
        }
      }
      // CNOT ring (0,1)(1,2)(2,3)(3,0)
      const int cqs[4] = {0, 1, 2, 3};
      const int tqs[4] = {1, 2, 3, 0};
#pragma unroll
      for (int gIdx = 0; gIdx < 4; ++gIdx) {
#pragma unroll
        for (int z = 0; z < 16; ++z) {
          if (((z >> cqs[gIdx]) & 1) && !((z >> tqs[gIdx]) & 1)) {
            int z1 = z | (1 << tqs[gIdx]);
            float tr = re[z], ti = im[z];
            re[z] = re[z1];  im[z] = im[z1];
            re[z1] = tr;     im[z1] = ti;
          }
        }
      }
    }
#pragma unroll
    for (int z = 0; z < 16; ++z) { Vre[z][tid] = re[z]; Vim[z][tid] = im[z]; }
  }
  __syncthreads();

  // ---- prologue: M formation ----
  {
    const int i = tid >> 6, a = (tid >> 2) & 15, b0 = (tid & 3) * 4;
    float ra[16], ia[16];
#pragma unroll
    for (int z = 0; z < 16; ++z) { ra[z] = Vre[z][a]; ia[z] = Vim[z][a]; }
#pragma unroll
    for (int k = 0; k < 4; ++k) {
      const int b = b0 + k;
      float acc = 0.f;
#pragma unroll
      for (int z = 0; z < 16; ++z) {
        float sg = ((z >> (3 - i)) & 1) ? -1.f : 1.f;
        acc += sg * (ra[z] * Vre[z][b] + ia[z] * Vim[z][b]);
      }
      Mlds[i][a][b] = acc;
    }
  }
  __syncthreads();

  // ---- main-loop invariants ----
  const int lane = tid & 63;
  const int wave = blockIdx.x * 4 + (tid >> 6);
  const int nwaves = gridDim.x * 4;
  const int g = lane >> 4;
  const int mz = lane & 15;

  float Mr[16];
#pragma unroll
  for (int k = 0; k < 16; ++k) Mr[k] = Mlds[g][mz][k];

  float b1r[4];
#pragma unroll
  for (int j = 0; j < 4; ++j) b1r[j] = b1[j];

  float wmuP[4], wlvP[4];
#pragma unroll
  for (int k = 0; k < 4; ++k) {
    wmuP[k] = Wmu[lane * 4 + (g ^ k)];
    wlvP[k] = Wlv[lane * 4 + (g ^ k)];
  }
  const float bmur = bmu[lane], blvr = blv[lane];
  const size_t lv_base = (size_t)B * 64;

  for (int r = wave; r < B; r += nwaves) {
    const float4 dv = *reinterpret_cast<const float4*>(dots + (size_t)r * 4);

    // ---- angles -> half-angle (cos, sin) ----
    float cq[4], sq[4];
    __sincosf(0.5f * fast_tanh(dv.x + b1r[0]), &sq[0], &cq[0]);
    __sincosf(0.5f * fast_tanh(dv.y + b1r[1]), &sq[1], &cq[1]);
    __sincosf(0.5f * fast_tanh(dv.z + b1r[2]), &sq[2], &cq[2]);
    __sincosf(0.5f * fast_tanh(dv.w + b1r[3]), &sq[3], &cq[3]);

    // rank-1 factors of the product state: sv[z] = A[z&3] * Bf[z>>2]
    const float A0 = cq[0] * cq[1], A1 = sq[0] * cq[1];
    const float A2 = cq[0] * sq[1], A3 = sq[0] * sq[1];
    const float B0 = cq[2] * cq[3], B1 = sq[2] * cq[3];
    const float B2 = cq[2] * sq[3], B3 = sq[2] * sq[3];

    // tdot = M_g[mz][:] . sv
    float t0 = fmaf(Mr[3], A3, fmaf(Mr[2], A2, fmaf(Mr[1], A1, Mr[0] * A0)));
    float t1 = fmaf(Mr[7], A3, fmaf(Mr[6], A2, fmaf(Mr[5], A1, Mr[4] * A0)));
    float t2 = fmaf(Mr[11], A3, fmaf(Mr[10], A2, fmaf(Mr[9], A1, Mr[8] * A0)));
    float t3 = fmaf(Mr[15], A3, fmaf(Mr[14], A2, fmaf(Mr[13], A1, Mr[12] * A0)));
    float tdot = fmaf(t3, B3, fmaf(t2, B2, fmaf(t1, B1, t0 * B0)));

    // sv[mz] via per-bit selects
    float svm = ((mz & 1) ? sq[0] : cq[0]);
    svm *= ((mz & 2) ? sq[1] : cq[1]);
    svm *= ((mz & 4) ? sq[2] : cq[2]);
    svm *= ((mz & 8) ? sq[3] : cq[3]);

    float pacc = tdot * svm;
#pragma unroll
    for (int off = 8; off; off >>= 1) pacc += __shfl_xor(pacc, off);
    // pacc = qf_g; exchange across 16-lane groups
    float v1 = __shfl_xor(pacc, 16);  // qf_{g^1}
    float v2 = __shfl_xor(pacc, 32);  // qf_{g^2}
    float v3 = __shfl_xor(v1, 32);    // qf_{g^3}

    float mu = fmaf(v3, wmuP[3], fmaf(v2, wmuP[2], fmaf(v1, wmuP[1], fmaf(pacc, wmuP[0], bmur))));
    float lv = fmaf(v3, wlvP[3], fmaf(v2, wlvP[2], fmaf(v1, wlvP[1], fmaf(pacc, wlvP[0], blvr))));
    __builtin_nontemporal_store(mu, out + (size_t)r * 64 + lane);
    __builtin_nontemporal_store(lv, out + lv_base + (size_t)r * 64 + lane);
  }
}

extern "C" void kernel_launch(void* const* d_in, const int* in_sizes, int n_in,
                              void* d_out, int out_size, void* d_ws, size_t ws_size,
                              hipStream_t stream) {
  const float* x   = (const float*)d_in[0];
  const float* W1  = (const float*)d_in[1];
  const float* b1  = (const float*)d_in[2];
  const float* qp  = (const float*)d_in[3];
  const float* Wmu = (const float*)d_in[4];
  const float* bmu = (const float*)d_in[5];
  const float* Wlv = (const float*)d_in[6];
  const float* blv = (const float*)d_in[7];
  float* out = (float*)d_out;
  float* dots = (float*)d_ws;  // B*4 floats = 512 KB scratch

  const int B = out_size / 128;  // out = mu(B,64) ++ logvar(B,64)

  // k1: 16 rows/wave, 4 waves/block -> 64 rows/block (round-15 shape, REP=4)
  int blocks1 = (B + 63) / 64;
  dots_kernel<<<blocks1, 256, 0, stream>>>(x, W1, dots, B);

  // k2: 4 waves/block, grid-stride rows
  int blocks2 = (B + 31) / 32;
  if (blocks2 > 1024) blocks2 = 1024;
  tail_kernel<<<blocks2, 256, 0, stream>>>(dots, b1, qp, Wmu, bmu, Wlv, blv,
                                           out, B);
}

// Round 20
// 41.250 us; speedup vs baseline: 2.3548x; 2.3548x over previous
//
#include <hip/hip_runtime.h>

typedef float f32x4 __attribute__((ext_vector_type(4)));

#define D_IN 1024

// tanh(x) = 1 - 2/(exp(2x)+1): v_exp + v_rcp, robust for all x
__device__ __forceinline__ float fast_tanh(float x) {
  float e = __expf(2.0f * x);
  return 1.0f - 2.0f * __builtin_amdgcn_rcpf(e + 1.0f);
}

// ---------------------------------------------------------------------------
// k1 v4: r15 shape (16 rows/wave, 4 lanes/row, 512 blocks, plain loads,
// W1 in LDS) with an explicit double-buffered load pipeline.
// Round-19 counters showed VGPR_Count=36 -> load depth ~4 -> 4.5 TB/s
// latency-bound. Two live 16-chunk buffers (~145 VGPR, free at the
// grid-limited 2 waves/SIMD) keep up to 32 loads in flight per lane.
// ---------------------------------------------------------------------------
__global__ __launch_bounds__(256, 1) void dots_kernel(
    const float* __restrict__ x, const float* __restrict__ W1,
    float* __restrict__ dots, int B) {
  __shared__ f32x4 W1L[1024];  // W1L[j*256 + i] = W1[j][4i..4i+3]

  const int tid = threadIdx.x;
  {
    const f32x4* wp = reinterpret_cast<const f32x4*>(W1);
#pragma unroll
    for (int k = 0; k < 4; ++k) W1L[k * 256 + tid] = wp[k * 256 + tid];
  }
  __syncthreads();

  const int lane = tid & 63;
  const int p = lane & 3;        // d-phase: lane owns chunks (c>>2)*16 + p*4 + (c&3)
  const int wave = blockIdx.x * 4 + (tid >> 6);
  const int row = wave * 16 + (lane >> 2);
  if (row >= B) return;

  const f32x4* xp4 = reinterpret_cast<const f32x4*>(x + (size_t)row * D_IN);

#define CHUNK_IDX(c) ((((c) >> 2) * 16) + (p * 4) + ((c) & 3))

  float acc[4] = {0.f, 0.f, 0.f, 0.f};
  f32x4 bufA[16], bufB[16];

  // prologue: fill both buffers (32 loads in flight)
#pragma unroll
  for (int k = 0; k < 16; ++k) bufA[k] = xp4[CHUNK_IDX(k)];
#pragma unroll
  for (int k = 0; k < 16; ++k) bufB[k] = xp4[CHUNK_IDX(16 + k)];

  // consume A (chunks 0..15), refill A with chunks 32..47
#pragma unroll
  for (int k = 0; k < 16; ++k) {
    const int wi = CHUNK_IDX(k);
    f32x4 xk = bufA[k];
#pragma unroll
    for (int j = 0; j < 4; ++j) {
      f32x4 w = W1L[j * 256 + wi];
      acc[j] = fmaf(xk.x, w.x, acc[j]);
      acc[j] = fmaf(xk.y, w.y, acc[j]);
      acc[j] = fmaf(xk.z, w.z, acc[j]);
      acc[j] = fmaf(xk.w, w.w, acc[j]);
    }
  }
#pragma unroll
  for (int k = 0; k < 16; ++k) bufA[k] = xp4[CHUNK_IDX(32 + k)];

  // consume B (chunks 16..31), refill B with chunks 48..63
#pragma unroll
  for (int k = 0; k < 16; ++k) {
    const int wi = CHUNK_IDX(16 + k);
    f32x4 xk = bufB[k];
#pragma unroll
    for (int j = 0; j < 4; ++j) {
      f32x4 w = W1L[j * 256 + wi];
      acc[j] = fmaf(xk.x, w.x, acc[j]);
      acc[j] = fmaf(xk.y, w.y, acc[j]);
      acc[j] = fmaf(xk.z, w.z, acc[j]);
      acc[j] = fmaf(xk.w, w.w, acc[j]);
    }
  }
#pragma unroll
  for (int k = 0; k < 16; ++k) bufB[k] = xp4[CHUNK_IDX(48 + k)];

  // consume A (chunks 32..47)
#pragma unroll
  for (int k = 0; k < 16; ++k) {
    const int wi = CHUNK_IDX(32 + k);
    f32x4 xk = bufA[k];
#pragma unroll
    for (int j = 0; j < 4; ++j) {
      f32x4 w = W1L[j * 256 + wi];
      acc[j] = fmaf(xk.x, w.x, acc[j]);
      acc[j] = fmaf(xk.y, w.y, acc[j]);
      acc[j] = fmaf(xk.z, w.z, acc[j]);
      acc[j] = fmaf(xk.w, w.w, acc[j]);
    }
  }
  // consume B (chunks 48..63)
#pragma unroll
  for (int k = 0; k < 16; ++k) {
    const int wi = CHUNK_IDX(48 + k);
    f32x4 xk = bufB[k];
#pragma unroll
    for (int j = 0; j < 4; ++j) {
      f32x4 w = W1L[j * 256 + wi];
      acc[j] = fmaf(xk.x, w.x, acc[j]);
      acc[j] = fmaf(xk.y, w.y, acc[j]);
      acc[j] = fmaf(xk.z, w.z, acc[j]);
      acc[j] = fmaf(xk.w, w.w, acc[j]);
    }
  }
#undef CHUNK_IDX

  // reduce each dot over the 4 phase-lanes (2 butterfly levels)
#pragma unroll
  for (int j = 0; j < 4; ++j) {
    acc[j] += __shfl_xor(acc[j], 1);
    acc[j] += __shfl_xor(acc[j], 2);
  }
  // lane p stores feature p -> dots[row][p]; 16B per row, coalesced
  float outv = (p == 0) ? acc[0] : (p == 1) ? acc[1] : (p == 2) ? acc[2] : acc[3];
  dots[(size_t)row * 4 + p] = outv;
}

// ---------------------------------------------------------------------------
// k2: tail (unchanged, validated). Per row: uniform 16B load of dots[r] ->
// tanh/sincos -> rank-1 product state -> qf_i = s^T M_i s -> mu/logvar.
// ---------------------------------------------------------------------------
__global__ __launch_bounds__(256) void tail_kernel(
    const float* __restrict__ dots, const float* __restrict__ b1,
    const float* __restrict__ theta,
    const float* __restrict__ Wmu, const float* __restrict__ bmu,
    const float* __restrict__ Wlv, const float* __restrict__ blv,
    float* __restrict__ out, int B) {
  __shared__ float Vre[16][17];
  __shared__ float Vim[16][17];
  __shared__ float Mlds[4][16][16];

  const int tid = threadIdx.x;

  // ---- prologue: evolve V on threads 0..15 ----
  if (tid < 16) {
    float re[16], im[16];
#pragma unroll
    for (int z = 0; z < 16; ++z) { re[z] = 0.f; im[z] = 0.f; }
    re[tid] = 1.f;
    for (int layer = 0; layer < 2; ++layer) {
#pragma unroll
      for (int q = 0; q < 4; ++q) {
        float th = theta[layer * 4 + q];
        float s, c;
        __sincosf(0.5f * th, &s, &c);
        // Rx
#pragma unroll
        for (int z = 0; z < 16; ++z) {
          if (!((z >> q) & 1)) {
            int z1 = z | (1 << q);
            float ar = re[z], ai = im[z], br = re[z1], bi = im[z1];
            re[z]  = c * ar + s * bi;  im[z]  = c * ai - s * br;
            re[z1] = c * br + s * ai;  im[z1] = c * bi - s * ar;
          }
        }
        // Ry
#pragma unroll
        for (int z = 0; z < 16; ++z) {
          if (!((z >> q) & 1)) {
            int z1 = z | (1 << q);
            float ar = re[z], ai = im[z], br = re[z1], bi = im[z1];
            re[z]  = c * ar - s * br;  im[z]  = c * ai - s * bi;
            re[z1] = s * ar + c * br;  im[z1] = s * ai + c * bi;
          }
        }
        // Rz
#pragma unroll
        for (int z = 0; z < 16; ++z) {
          if (!((z >> q) & 1)) {
            int z1 = z | (1 << q);
            float ar = re[z], ai = im[z], br = re[z1], bi = im[z1];
            re[z]  = c * ar + s * ai;  im[z]  = c * ai - s * ar;
            re[z1] = c * br - s * bi;  im[z1] = c * bi + s * br;
          }
        }
      }
      // CNOT ring (0,1)(1,2)(2,3)(3,0)
      const int cqs[4] = {0, 1, 2, 3};
      const int tqs[4] = {1, 2, 3, 0};
#pragma unroll
      for (int gIdx = 0; gIdx < 4; ++gIdx) {
#pragma unroll
        for (int z = 0; z < 16; ++z) {
          if (((z >> cqs[gIdx]) & 1) && !((z >> tqs[gIdx]) & 1)) {
            int z1 = z | (1 << tqs[gIdx]);
            float tr = re[z], ti = im[z];
            re[z] = re[z1];  im[z] = im[z1];
            re[z1] = tr;     im[z1] = ti;
          }
        }
      }
    }
#pragma unroll
    for (int z = 0; z < 16; ++z) { Vre[z][tid] = re[z]; Vim[z][tid] = im[z]; }
  }
  __syncthreads();

  // ---- prologue: M formation ----
  {
    const int i = tid >> 6, a = (tid >> 2) & 15, b0 = (tid & 3) * 4;
    float ra[16], ia[16];
#pragma unroll
    for (int z = 0; z < 16; ++z) { ra[z] = Vre[z][a]; ia[z] = Vim[z][a]; }
#pragma unroll
    for (int k = 0; k < 4; ++k) {
      const int b = b0 + k;
      float acc = 0.f;
#pragma unroll
      for (int z = 0; z < 16; ++z) {
        float sg = ((z >> (3 - i)) & 1) ? -1.f : 1.f;
        acc += sg * (ra[z] * Vre[z][b] + ia[z] * Vim[z][b]);
      }
      Mlds[i][a][b] = acc;
    }
  }
  __syncthreads();

  // ---- main-loop invariants ----
  const int lane = tid & 63;
  const int wave = blockIdx.x * 4 + (tid >> 6);
  const int nwaves = gridDim.x * 4;
  const int g = lane >> 4;
  const int mz = lane & 15;

  float Mr[16];
#pragma unroll
  for (int k = 0; k < 16; ++k) Mr[k] = Mlds[g][mz][k];

  float b1r[4];
#pragma unroll
  for (int j = 0; j < 4; ++j) b1r[j] = b1[j];

  float wmuP[4], wlvP[4];
#pragma unroll
  for (int k = 0; k < 4; ++k) {
    wmuP[k] = Wmu[lane * 4 + (g ^ k)];
    wlvP[k] = Wlv[lane * 4 + (g ^ k)];
  }
  const float bmur = bmu[lane], blvr = blv[lane];
  const size_t lv_base = (size_t)B * 64;

  for (int r = wave; r < B; r += nwaves) {
    const float4 dv = *reinterpret_cast<const float4*>(dots + (size_t)r * 4);

    // ---- angles -> half-angle (cos, sin) ----
    float cq[4], sq[4];
    __sincosf(0.5f * fast_tanh(dv.x + b1r[0]), &sq[0], &cq[0]);
    __sincosf(0.5f * fast_tanh(dv.y + b1r[1]), &sq[1], &cq[1]);
    __sincosf(0.5f * fast_tanh(dv.z + b1r[2]), &sq[2], &cq[2]);
    __sincosf(0.5f * fast_tanh(dv.w + b1r[3]), &sq[3], &cq[3]);

    // rank-1 factors of the product state: sv[z] = A[z&3] * Bf[z>>2]
    const float A0 = cq[0] * cq[1], A1 = sq[0] * cq[1];
    const float A2 = cq[0] * sq[1], A3 = sq[0] * sq[1];
    const float B0 = cq[2] * cq[3], B1 = sq[2] * cq[3];
    const float B2 = cq[2] * sq[3], B3 = sq[2] * sq[3];

    // tdot = M_g[mz][:] . sv
    float t0 = fmaf(Mr[3], A3, fmaf(Mr[2], A2, fmaf(Mr[1], A1, Mr[0] * A0)));
    float t1 = fmaf(Mr[7], A3, fmaf(Mr[6], A2, fmaf(Mr[5], A1, Mr[4] * A0)));
    float t2 = fmaf(Mr[11], A3, fmaf(Mr[10], A2, fmaf(Mr[9], A1, Mr[8] * A0)));
    float t3 = fmaf(Mr[15], A3, fmaf(Mr[14], A2, fmaf(Mr[13], A1, Mr[12] * A0)));
    float tdot = fmaf(t3, B3, fmaf(t2, B2, fmaf(t1, B1, t0 * B0)));

    // sv[mz] via per-bit selects
    float svm = ((mz & 1) ? sq[0] : cq[0]);
    svm *= ((mz & 2) ? sq[1] : cq[1]);
    svm *= ((mz & 4) ? sq[2] : cq[2]);
    svm *= ((mz & 8) ? sq[3] : cq[3]);

    float pacc = tdot * svm;
#pragma unroll
    for (int off = 8; off; off >>= 1) pacc += __shfl_xor(pacc, off);
    // pacc = qf_g; exchange across 16-lane groups
    float v1 = __shfl_xor(pacc, 16);  // qf_{g^1}
    float v2 = __shfl_xor(pacc, 32);  // qf_{g^2}
    float v3 = __shfl_xor(v1, 32);    // qf_{g^3}

    float mu = fmaf(v3, wmuP[3], fmaf(v2, wmuP[2], fmaf(v1, wmuP[1], fmaf(pacc, wmuP[0], bmur))));
    float lv = fmaf(v3, wlvP[3], fmaf(v2, wlvP[2], fmaf(v1, wlvP[1], fmaf(pacc, wlvP[0], blvr))));
    __builtin_nontemporal_store(mu, out + (size_t)r * 64 + lane);
    __builtin_nontemporal_store(lv, out + lv_base + (size_t)r * 64 + lane);
  }
}

extern "C" void kernel_launch(void* const* d_in, const int* in_sizes, int n_in,
                              void* d_out, int out_size, void* d_ws, size_t ws_size,
                              hipStream_t stream) {
  const float* x   = (const float*)d_in[0];
  const float* W1  = (const float*)d_in[1];
  const float* b1  = (const float*)d_in[2];
  const float* qp  = (const float*)d_in[3];
  const float* Wmu = (const float*)d_in[4];
  const float* bmu = (const float*)d_in[5];
  const float* Wlv = (const float*)d_in[6];
  const float* blv = (const float*)d_in[7];
  float* out = (float*)d_out;
  float* dots = (float*)d_ws;  // B*4 floats = 512 KB scratch

  const int B = out_size / 128;  // out = mu(B,64) ++ logvar(B,64)

  // k1: 16 rows/wave, 4 waves/block -> 64 rows/block; 512 blocks
  int blocks1 = (B + 63) / 64;
  dots_kernel<<<blocks1, 256, 0, stream>>>(x, W1, dots, B);

  // k2: 4 waves/block, grid-stride rows
  int blocks2 = (B + 31) / 32;
  if (blocks2 > 1024) blocks2 = 1024;
  tail_kernel<<<blocks2, 256, 0, stream>>>(dots, b1, qp, Wmu, bmu, Wlv, blv,
                                           out, B);
}

// Round 23
// 38.899 us; speedup vs baseline: 2.4971x; 1.0604x over previous
//
#include <hip/hip_runtime.h>

typedef float f32x4 __attribute__((ext_vector_type(4)));

#define D_IN 1024

// tanh(x) = 1 - 2/(exp(2x)+1): v_exp + v_rcp, robust for all x
__device__ __forceinline__ float fast_tanh(float x) {
  float e = __expf(2.0f * x);
  return 1.0f - 2.0f * __builtin_amdgcn_rcpf(e + 1.0f);
}

// ---------------------------------------------------------------------------
// Fused single kernel, two phases, LDS dots handoff, no inter-phase barrier:
//  phase 1 (per wave): r19's measured-best dot body (16 rows/wave, 4 lanes/row,
//           plain loads, 2-level reduce) -> dots_lds[64][4].
//  phase 2 (per wave): validated tail on its OWN 16 rows, dv from LDS
//           broadcast; trig -> rank-1 qform -> 7-shfl -> mu/logvar stores.
// Each wave reads only its own phase-1 LDS writes -> no __syncthreads between
// phases; tails overlap other waves' loads.
// ---------------------------------------------------------------------------
__global__ __launch_bounds__(256, 1) void fused_qenc_kernel(
    const float* __restrict__ x, const float* __restrict__ W1,
    const float* __restrict__ b1, const float* __restrict__ theta,
    const float* __restrict__ Wmu, const float* __restrict__ bmu,
    const float* __restrict__ Wlv, const float* __restrict__ blv,
    float* __restrict__ out, int B) {
  __shared__ f32x4 W1L[1024];          // 16 KB: W1L[j*256 + i] = W1[j][4i..4i+3]
  __shared__ float Vre[16][17];
  __shared__ float Vim[16][17];
  __shared__ float Mlds[4][16][16];
  __shared__ f32x4 dotsL[64];          // 1 KB: dots for this block's 64 rows

  const int tid = threadIdx.x;

  // ---- prologue A: stage W1 into LDS ----
  {
    const f32x4* wp = reinterpret_cast<const f32x4*>(W1);
#pragma unroll
    for (int k = 0; k < 4; ++k) W1L[k * 256 + tid] = wp[k * 256 + tid];
  }

  // ---- prologue B: evolve V on threads 0..15 (validated) ----
  if (tid < 16) {
    float re[16], im[16];
#pragma unroll
    for (int z = 0; z < 16; ++z) { re[z] = 0.f; im[z] = 0.f; }
    re[tid] = 1.f;
    for (int layer = 0; layer < 2; ++layer) {
#pragma unroll
      for (int q = 0; q < 4; ++q) {
        float th = theta[layer * 4 + q];
        float s, c;
        __sincosf(0.5f * th, &s, &c);
        // Rx
#pragma unroll
        for (int z = 0; z < 16; ++z) {
          if (!((z >> q) & 1)) {
            int z1 = z | (1 << q);
            float ar = re[z], ai = im[z], br = re[z1], bi = im[z1];
            re[z]  = c * ar + s * bi;  im[z]  = c * ai - s * br;
            re[z1] = c * br + s * ai;  im[z1] = c * bi - s * ar;
          }
        }
        // Ry
#pragma unroll
        for (int z = 0; z < 16; ++z) {
          if (!((z >> q) & 1)) {
            int z1 = z | (1 << q);
            float ar = re[z], ai = im[z], br = re[z1], bi = im[z1];
            re[z]  = c * ar - s * br;  im[z]  = c * ai - s * bi;
            re[z1] = s * ar + c * br;  im[z1] = s * ai + c * bi;
          }
        }
        // Rz
#pragma unroll
        for (int z = 0; z < 16; ++z) {
          if (!((z >> q) & 1)) {
            int z1 = z | (1 << q);
            float ar = re[z], ai = im[z], br = re[z1], bi = im[z1];
            re[z]  = c * ar + s * ai;  im[z]  = c * ai - s * ar;
            re[z1] = c * br - s * bi;  im[z1] = c * bi + s * br;
          }
        }
      }
      // CNOT ring (0,1)(1,2)(2,3)(3,0)
      const int cqs[4] = {0, 1, 2, 3};
      const int tqs[4] = {1, 2, 3, 0};
#pragma unroll
      for (int gIdx = 0; gIdx < 4; ++gIdx) {
#pragma unroll
        for (int z = 0; z < 16; ++z) {
          if (((z >> cqs[gIdx]) & 1) && !((z >> tqs[gIdx]) & 1)) {
            int z1 = z | (1 << tqs[gIdx]);
            float tr = re[z], ti = im[z];
            re[z] = re[z1];  im[z] = im[z1];
            re[z1] = tr;     im[z1] = ti;
          }
        }
      }
    }
#pragma unroll
    for (int z = 0; z < 16; ++z) { Vre[z][tid] = re[z]; Vim[z][tid] = im[z]; }
  }
  __syncthreads();

  // ---- prologue C: M formation on 256 threads (validated) ----
  {
    const int i = tid >> 6, a = (tid >> 2) & 15, b0 = (tid & 3) * 4;
    float ra[16], ia[16];
#pragma unroll
    for (int z = 0; z < 16; ++z) { ra[z] = Vre[z][a]; ia[z] = Vim[z][a]; }
#pragma unroll
    for (int k = 0; k < 4; ++k) {
      const int b = b0 + k;
      float acc = 0.f;
#pragma unroll
      for (int z = 0; z < 16; ++z) {
        float sg = ((z >> (3 - i)) & 1) ? -1.f : 1.f;
        acc += sg * (ra[z] * Vre[z][b] + ia[z] * Vim[z][b]);
      }
      Mlds[i][a][b] = acc;
    }
  }
  __syncthreads();

  // ---- invariants (hoisted; latency overlaps phase 1) ----
  const int lane = tid & 63;
  const int widx = tid >> 6;                   // wave index in block
  const int wave = blockIdx.x * 4 + widx;
  const int g = lane >> 4;
  const int mz = lane & 15;
  const int p = lane & 3;

  float Mr[16];
#pragma unroll
  for (int k = 0; k < 16; ++k) Mr[k] = Mlds[g][mz][k];
  float b1r[4];
#pragma unroll
  for (int j = 0; j < 4; ++j) b1r[j] = b1[j];
  float wmuP[4], wlvP[4];
#pragma unroll
  for (int k = 0; k < 4; ++k) {
    wmuP[k] = Wmu[lane * 4 + (g ^ k)];
    wlvP[k] = Wlv[lane * 4 + (g ^ k)];
  }
  const float bmur = bmu[lane], blvr = blv[lane];
  const size_t lv_base = (size_t)B * 64;

  // ---- phase 1: dots for this wave's 16 rows (r19 validated body) ----
  {
    const int row = wave * 16 + (lane >> 2);
    if (row < B) {
      const float* xr = x + (size_t)row * D_IN;
      float acc[4] = {0.f, 0.f, 0.f, 0.f};
#pragma unroll
      for (int gg = 0; gg < 16; ++gg) {
        const int db = gg * 64 + p * 16;
        f32x4 xv[4];
#pragma unroll
        for (int k = 0; k < 4; ++k)
          xv[k] = *reinterpret_cast<const f32x4*>(xr + db + 4 * k);
#pragma unroll
        for (int k = 0; k < 4; ++k) {
          const int wi = (db >> 2) + k;
          f32x4 xk = xv[k];
#pragma unroll
          for (int j = 0; j < 4; ++j) {
            f32x4 w = W1L[j * 256 + wi];
            acc[j] = fmaf(xk.x, w.x, acc[j]);
            acc[j] = fmaf(xk.y, w.y, acc[j]);
            acc[j] = fmaf(xk.z, w.z, acc[j]);
            acc[j] = fmaf(xk.w, w.w, acc[j]);
          }
        }
      }
      // 2-level reduce over the 4 phase-lanes
#pragma unroll
      for (int j = 0; j < 4; ++j) {
        acc[j] += __shfl_xor(acc[j], 1);
        acc[j] += __shfl_xor(acc[j], 2);
      }
      float outv = (p == 0) ? acc[0] : (p == 1) ? acc[1] : (p == 2) ? acc[2] : acc[3];
      // lane writes component p of its row's dots into LDS
      reinterpret_cast<float*>(&dotsL[widx * 16 + (lane >> 2)])[p] = outv;
    }
  }
  // no barrier: each wave reads only its own dotsL entries below

  // ---- phase 2: tail for this wave's 16 rows (validated body, dv from LDS) ----
#pragma unroll 1
  for (int rr = 0; rr < 16; ++rr) {
    const int r = wave * 16 + rr;
    if (r >= B) break;
    f32x4 dv = dotsL[widx * 16 + rr];  // uniform address -> LDS broadcast

    float cq[4], sq[4];
    __sincosf(0.5f * fast_tanh(dv.x + b1r[0]), &sq[0], &cq[0]);
    __sincosf(0.5f * fast_tanh(dv.y + b1r[1]), &sq[1], &cq[1]);
    __sincosf(0.5f * fast_tanh(dv.z + b1r[2]), &sq[2], &cq[2]);
    __sincosf(0.5f * fast_tanh(dv.w + b1r[3]), &sq[3], &cq[3]);

    // rank-1 factors of the product state: sv[z] = A[z&3] * Bf[z>>2]
    const float A0 = cq[0] * cq[1], A1 = sq[0] * cq[1];
    const float A2 = cq[0] * sq[1], A3 = sq[0] * sq[1];
    const float B0 = cq[2] * cq[3], B1 = sq[2] * cq[3];
    const float B2 = cq[2] * sq[3], B3 = sq[2] * sq[3];

    // tdot = M_g[mz][:] . sv
    float t0 = fmaf(Mr[3], A3, fmaf(Mr[2], A2, fmaf(Mr[1], A1, Mr[0] * A0)));
    float t1 = fmaf(Mr[7], A3, fmaf(Mr[6], A2, fmaf(Mr[5], A1, Mr[4] * A0)));
    float t2 = fmaf(Mr[11], A3, fmaf(Mr[10], A2, fmaf(Mr[9], A1, Mr[8] * A0)));
    float t3 = fmaf(Mr[15], A3, fmaf(Mr[14], A2, fmaf(Mr[13], A1, Mr[12] * A0)));
    float tdot = fmaf(t3, B3, fmaf(t2, B2, fmaf(t1, B1, t0 * B0)));

    // sv[mz] via per-bit selects
    float svm = ((mz & 1) ? sq[0] : cq[0]);
    svm *= ((mz & 2) ? sq[1] : cq[1]);
    svm *= ((mz & 4) ? sq[2] : cq[2]);
    svm *= ((mz & 8) ? sq[3] : cq[3]);

    float pacc = tdot * svm;
#pragma unroll
    for (int off = 8; off; off >>= 1) pacc += __shfl_xor(pacc, off);
    // pacc = qf_g; exchange across 16-lane groups
    float v1 = __shfl_xor(pacc, 16);  // qf_{g^1}
    float v2 = __shfl_xor(pacc, 32);  // qf_{g^2}
    float v3 = __shfl_xor(v1, 32);    // qf_{g^3}

    float mu = fmaf(v3, wmuP[3], fmaf(v2, wmuP[2], fmaf(v1, wmuP[1], fmaf(pacc, wmuP[0], bmur))));
    float lv = fmaf(v3, wlvP[3], fmaf(v2, wlvP[2], fmaf(v1, wlvP[1], fmaf(pacc, wlvP[0], blvr))));
    __builtin_nontemporal_store(mu, out + (size_t)r * 64 + lane);
    __builtin_nontemporal_store(lv, out + lv_base + (size_t)r * 64 + lane);
  }
}

extern "C" void kernel_launch(void* const* d_in, const int* in_sizes, int n_in,
                              void* d_out, int out_size, void* d_ws, size_t ws_size,
                              hipStream_t stream) {
  const float* x   = (const float*)d_in[0];
  const float* W1  = (const float*)d_in[1];
  const float* b1  = (const float*)d_in[2];
  const float* qp  = (const float*)d_in[3];
  const float* Wmu = (const float*)d_in[4];
  const float* bmu = (const float*)d_in[5];
  const float* Wlv = (const float*)d_in[6];
  const float* blv = (const float*)d_in[7];
  float* out = (float*)d_out;

  const int B = out_size / 128;  // out = mu(B,64) ++ logvar(B,64)

  // 64 rows/block (4 waves x 16 rows); B=32768 -> 512 blocks (2 blocks/CU)
  int blocks = (B + 63) / 64;
  fused_qenc_kernel<<<blocks, 256, 0, stream>>>(x, W1, b1, qp, Wmu, bmu, Wlv, blv,
                                                out, B);
}

// Round 24
// 33.905 us; speedup vs baseline: 2.8649x; 1.1473x over previous
//
#include <hip/hip_runtime.h>

typedef float f32x4 __attribute__((ext_vector_type(4)));

#define D_IN 1024

// tanh(x) = 1 - 2/(exp(2x)+1): v_exp + v_rcp, robust for all x
__device__ __forceinline__ float fast_tanh(float x) {
  float e = __expf(2.0f * x);
  return 1.0f - 2.0f * __builtin_amdgcn_rcpf(e + 1.0f);
}

// ---------------------------------------------------------------------------
// Fused kernel v2: V/M prologue OFF the load critical path.
//  - wave 0: V-evolve (lanes 0..15) -> M-formation (64 lanes) -> LDS flag ->
//    then its phase 1 (late).
//  - waves 1..3: phase 1 immediately after the W1 barrier; spin on the flag
//    only AFTER phase 1 (M is needed only for phase 2).
// Phase 1 = r19's measured dot body (16 rows/wave, 4 lanes/row, plain loads).
// Phase 2 = validated tail, dv from LDS, Mr read after the flag.
// ---------------------------------------------------------------------------
__global__ __launch_bounds__(256, 1) void fused_qenc_kernel(
    const float* __restrict__ x, const float* __restrict__ W1,
    const float* __restrict__ b1, const float* __restrict__ theta,
    const float* __restrict__ Wmu, const float* __restrict__ bmu,
    const float* __restrict__ Wlv, const float* __restrict__ blv,
    float* __restrict__ out, int B) {
  __shared__ f32x4 W1L[1024];          // 16 KB
  __shared__ float Vre[16][17];
  __shared__ float Vim[16][17];
  __shared__ float Mlds[4][16][16];
  __shared__ f32x4 dotsL[64];          // 1 KB
  __shared__ volatile int mReady;

  const int tid = threadIdx.x;
  if (tid == 0) mReady = 0;

  // ---- stage W1 into LDS (all 256 threads) ----
  {
    const f32x4* wp = reinterpret_cast<const f32x4*>(W1);
#pragma unroll
    for (int k = 0; k < 4; ++k) W1L[k * 256 + tid] = wp[k * 256 + tid];
  }
  __syncthreads();  // W1L ready; mReady=0 visible

  const int lane = tid & 63;
  const int widx = tid >> 6;
  const int wave = blockIdx.x * 4 + widx;
  const int g = lane >> 4;
  const int mz = lane & 15;
  const int p = lane & 3;

  // global invariant loads (issue early; overlap with everything)
  float b1r[4];
#pragma unroll
  for (int j = 0; j < 4; ++j) b1r[j] = b1[j];
  float wmuP[4], wlvP[4];
#pragma unroll
  for (int k = 0; k < 4; ++k) {
    wmuP[k] = Wmu[lane * 4 + (g ^ k)];
    wlvP[k] = Wlv[lane * 4 + (g ^ k)];
  }
  const float bmur = bmu[lane], blvr = blv[lane];
  const size_t lv_base = (size_t)B * 64;

  // ---- wave 0 only: V-evolve + M-formation + flag ----
  if (widx == 0) {
    if (lane < 16) {
      float re[16], im[16];
#pragma unroll
      for (int z = 0; z < 16; ++z) { re[z] = 0.f; im[z] = 0.f; }
      re[lane] = 1.f;
      for (int layer = 0; layer < 2; ++layer) {
#pragma unroll
        for (int q = 0; q < 4; ++q) {
          float th = theta[layer * 4 + q];
          float s, c;
          __sincosf(0.5f * th, &s, &c);
          // Rx
#pragma unroll
          for (int z = 0; z < 16; ++z) {
            if (!((z >> q) & 1)) {
              int z1 = z | (1 << q);
              float ar = re[z], ai = im[z], br = re[z1], bi = im[z1];
              re[z]  = c * ar + s * bi;  im[z]  = c * ai - s * br;
              re[z1] = c * br + s * ai;  im[z1] = c * bi - s * ar;
            }
          }
          // Ry
#pragma unroll
          for (int z = 0; z < 16; ++z) {
            if (!((z >> q) & 1)) {
              int z1 = z | (1 << q);
              float ar = re[z], ai = im[z], br = re[z1], bi = im[z1];
              re[z]  = c * ar - s * br;  im[z]  = c * ai - s * bi;
              re[z1] = s * ar + c * br;  im[z1] = s * ai + c * bi;
            }
          }
          // Rz
#pragma unroll
          for (int z = 0; z < 16; ++z) {
            if (!((z >> q) & 1)) {
              int z1 = z | (1 << q);
              float ar = re[z], ai = im[z], br = re[z1], bi = im[z1];
              re[z]  = c * ar + s * ai;  im[z]  = c * ai - s * ar;
              re[z1] = c * br - s * bi;  im[z1] = c * bi + s * br;
            }
          }
        }
        // CNOT ring (0,1)(1,2)(2,3)(3,0)
        const int cqs[4] = {0, 1, 2, 3};
        const int tqs[4] = {1, 2, 3, 0};
#pragma unroll
        for (int gIdx = 0; gIdx < 4; ++gIdx) {
#pragma unroll
          for (int z = 0; z < 16; ++z) {
            if (((z >> cqs[gIdx]) & 1) && !((z >> tqs[gIdx]) & 1)) {
              int z1 = z | (1 << tqs[gIdx]);
              float tr = re[z], ti = im[z];
              re[z] = re[z1];  im[z] = im[z1];
              re[z1] = tr;     im[z1] = ti;
            }
          }
        }
      }
#pragma unroll
      for (int z = 0; z < 16; ++z) { Vre[z][lane] = re[z]; Vim[z][lane] = im[z]; }
    }
    // same-wave LDS ordering: V writes above complete before reads below
    {
      const int i = lane >> 4, a = lane & 15;
      float ra[16], ia[16];
#pragma unroll
      for (int z = 0; z < 16; ++z) { ra[z] = Vre[z][a]; ia[z] = Vim[z][a]; }
#pragma unroll
      for (int b = 0; b < 16; ++b) {
        float acc = 0.f;
#pragma unroll
        for (int z = 0; z < 16; ++z) {
          float sg = ((z >> (3 - i)) & 1) ? -1.f : 1.f;
          acc += sg * (ra[z] * Vre[z][b] + ia[z] * Vim[z][b]);
        }
        Mlds[i][a][b] = acc;
      }
    }
    __threadfence_block();
    if (lane == 0) mReady = 1;
  }

  // ---- phase 1: dots for this wave's 16 rows (r19 validated body) ----
  {
    const int row = wave * 16 + (lane >> 2);
    if (row < B) {
      const float* xr = x + (size_t)row * D_IN;
      float acc[4] = {0.f, 0.f, 0.f, 0.f};
#pragma unroll
      for (int gg = 0; gg < 16; ++gg) {
        const int db = gg * 64 + p * 16;
        f32x4 xv[4];
#pragma unroll
        for (int k = 0; k < 4; ++k)
          xv[k] = *reinterpret_cast<const f32x4*>(xr + db + 4 * k);
#pragma unroll
        for (int k = 0; k < 4; ++k) {
          const int wi = (db >> 2) + k;
          f32x4 xk = xv[k];
#pragma unroll
          for (int j = 0; j < 4; ++j) {
            f32x4 w = W1L[j * 256 + wi];
            acc[j] = fmaf(xk.x, w.x, acc[j]);
            acc[j] = fmaf(xk.y, w.y, acc[j]);
            acc[j] = fmaf(xk.z, w.z, acc[j]);
            acc[j] = fmaf(xk.w, w.w, acc[j]);
          }
        }
      }
#pragma unroll
      for (int j = 0; j < 4; ++j) {
        acc[j] += __shfl_xor(acc[j], 1);
        acc[j] += __shfl_xor(acc[j], 2);
      }
      float outv = (p == 0) ? acc[0] : (p == 1) ? acc[1] : (p == 2) ? acc[2] : acc[3];
      reinterpret_cast<float*>(&dotsL[widx * 16 + (lane >> 2)])[p] = outv;
    }
  }

  // ---- waves 1..3: wait for M (wave 0 set the flag before its phase 1) ----
  if (widx != 0) {
    while (mReady == 0) __builtin_amdgcn_s_sleep(1);
  }
  __threadfence_block();  // acquire: Mlds writes visible

  float Mr[16];
#pragma unroll
  for (int k = 0; k < 16; ++k) Mr[k] = Mlds[g][mz][k];

  // ---- phase 2: tail for this wave's 16 rows (validated body) ----
#pragma unroll 1
  for (int rr = 0; rr < 16; ++rr) {
    const int r = wave * 16 + rr;
    if (r >= B) break;
    f32x4 dv = dotsL[widx * 16 + rr];  // uniform address -> LDS broadcast

    float cq[4], sq[4];
    __sincosf(0.5f * fast_tanh(dv.x + b1r[0]), &sq[0], &cq[0]);
    __sincosf(0.5f * fast_tanh(dv.y + b1r[1]), &sq[1], &cq[1]);
    __sincosf(0.5f * fast_tanh(dv.z + b1r[2]), &sq[2], &cq[2]);
    __sincosf(0.5f * fast_tanh(dv.w + b1r[3]), &sq[3], &cq[3]);

    // rank-1 factors of the product state: sv[z] = A[z&3] * Bf[z>>2]
    const float A0 = cq[0] * cq[1], A1 = sq[0] * cq[1];
    const float A2 = cq[0] * sq[1], A3 = sq[0] * sq[1];
    const float B0 = cq[2] * cq[3], B1 = sq[2] * cq[3];
    const float B2 = cq[2] * sq[3], B3 = sq[2] * sq[3];

    // tdot = M_g[mz][:] . sv
    float t0 = fmaf(Mr[3], A3, fmaf(Mr[2], A2, fmaf(Mr[1], A1, Mr[0] * A0)));
    float t1 = fmaf(Mr[7], A3, fmaf(Mr[6], A2, fmaf(Mr[5], A1, Mr[4] * A0)));
    float t2 = fmaf(Mr[11], A3, fmaf(Mr[10], A2, fmaf(Mr[9], A1, Mr[8] * A0)));
    float t3 = fmaf(Mr[15], A3, fmaf(Mr[14], A2, fmaf(Mr[13], A1, Mr[12] * A0)));
    float tdot = fmaf(t3, B3, fmaf(t2, B2, fmaf(t1, B1, t0 * B0)));

    // sv[mz] via per-bit selects
    float svm = ((mz & 1) ? sq[0] : cq[0]);
    svm *= ((mz & 2) ? sq[1] : cq[1]);
    svm *= ((mz & 4) ? sq[2] : cq[2]);
    svm *= ((mz & 8) ? sq[3] : cq[3]);

    float pacc = tdot * svm;
#pragma unroll
    for (int off = 8; off; off >>= 1) pacc += __shfl_xor(pacc, off);
    // pacc = qf_g; exchange across 16-lane groups
    float v1 = __shfl_xor(pacc, 16);  // qf_{g^1}
    float v2 = __shfl_xor(pacc, 32);  // qf_{g^2}
    float v3 = __shfl_xor(v1, 32);    // qf_{g^3}

    float mu = fmaf(v3, wmuP[3], fmaf(v2, wmuP[2], fmaf(v1, wmuP[1], fmaf(pacc, wmuP[0], bmur))));
    float lv = fmaf(v3, wlvP[3], fmaf(v2, wlvP[2], fmaf(v1, wlvP[1], fmaf(pacc, wlvP[0], blvr))));
    __builtin_nontemporal_store(mu, out + (size_t)r * 64 + lane);
    __builtin_nontemporal_store(lv, out + lv_base + (size_t)r * 64 + lane);
  }
}

extern "C" void kernel_launch(void* const* d_in, const int* in_sizes, int n_in,
                              void* d_out, int out_size, void* d_ws, size_t ws_size,
                              hipStream_t stream) {
  const float* x   = (const float*)d_in[0];
  const float* W1  = (const float*)d_in[1];
  const float* b1  = (const float*)d_in[2];
  const float* qp  = (const float*)d_in[3];
  const float* Wmu = (const float*)d_in[4];
  const float* bmu = (const float*)d_in[5];
  const float* Wlv = (const float*)d_in[6];
  const float* blv = (const float*)d_in[7];
  float* out = (float*)d_out;

  const int B = out_size / 128;  // out = mu(B,64) ++ logvar(B,64)

  // 64 rows/block (4 waves x 16 rows); B=32768 -> 512 blocks
  int blocks = (B + 63) / 64;
  fused_qenc_kernel<<<blocks, 256, 0, stream>>>(x, W1, b1, qp, Wmu, bmu, Wlv, blv,
                                                out, B);
}